// Round 6
// baseline (115.078 us; speedup 1.0000x reference)
//
#include <hip/hip_runtime.h>

#define NB   8
#define S_   1024
#define DIN  1280
#define RANK 64
#define DOUT 1280
#define DOWN (RANK * DIN)          // 81920
#define EMB  (DOWN + DOUT * RANK)  // 163840
#define XSTR 648                   // down-kernel LDS row stride (bf16): 1296 B

typedef __bf16 bf16x8 __attribute__((ext_vector_type(8)));
typedef __bf16 bf16x4 __attribute__((ext_vector_type(4)));
typedef float  f32x4  __attribute__((ext_vector_type(4)));

// ws layout: [ew: 8*163840 bf16 = 2.62 MB][ph: 2*8*64*16*64 fp32 = 4.19 MB]
#define PH_OFF (NB * EMB)          // elem offset (bf16 elems) -> cast separately

__device__ __forceinline__ bf16x8 cvt8(float4 a, float4 b) {
    bf16x8 r;
    r[0] = (__bf16)a.x; r[1] = (__bf16)a.y; r[2] = (__bf16)a.z; r[3] = (__bf16)a.w;
    r[4] = (__bf16)b.x; r[5] = (__bf16)b.y; r[6] = (__bf16)b.z; r[7] = (__bf16)b.w;
    return r;
}

// ---------------- K1: embed fp32 -> bf16 ----------------
__global__ __launch_bounds__(256) void cvt_embed(const float* __restrict__ src,
                                                 __bf16* __restrict__ dst, int n8) {
    const int i = blockIdx.x * 256 + threadIdx.x;
    if (i < n8) {
        const float4* s = reinterpret_cast<const float4*>(src) + (size_t)i * 2;
        float4 f0 = s[0], f1 = s[1];
        *reinterpret_cast<bf16x8*>(dst + (size_t)i * 8) = cvt8(f0, f1);
    }
}

// ---------------- K2: partial h = x @ w_down^T (K split 2 across blocks) ----
// grid 1024 = 8b x 64 st x 2 kh; 256 thr (4 waves = 4 n-tiles); 4 blocks/CU.
// Stage 16x640 fp32 x-chunk -> bf16 LDS (coalesced), 1 barrier, 20 k-steps.
__global__ __launch_bounds__(256, 4) void lora_down(const float* __restrict__ x,
                                                    const __bf16* __restrict__ ew,
                                                    float* __restrict__ ph) {
    __shared__ __bf16 xls[16 * XSTR];   // 20.7 KB

    const int bid  = blockIdx.x;
    const int b    = bid & 7;
    const int st   = (bid >> 3) & 63;
    const int kh   = bid >> 9;          // 0,1
    const int t    = threadIdx.x;
    const int w    = t >> 6;            // n-tile 0..3
    const int l    = t & 63;
    const int quad = l >> 4;
    const int lc   = l & 15;
    const int dq   = quad * 8;

    // stage x chunk: 16 rows x 640 fp32, 16 thr/row, coalesced float4
    {
        const int row = t >> 4;
        const int c   = t & 15;
        const float4* src = reinterpret_cast<const float4*>(
            x + (size_t)(b * S_ + st * 16 + row) * DIN + kh * 640);
        __bf16* drow = xls + row * XSTR;
#pragma unroll
        for (int j = 0; j < 10; ++j) {
            float4 f = src[c + 16 * j];
            bf16x4 v;
            v[0]=(__bf16)f.x; v[1]=(__bf16)f.y; v[2]=(__bf16)f.z; v[3]=(__bf16)f.w;
            *reinterpret_cast<bf16x4*>(drow + (c + 16 * j) * 4) = v;
        }
    }
    __syncthreads();

    const __bf16* wdrow = ew + (size_t)b * EMB + (size_t)(w * 16 + lc) * DIN + kh * 640;
    const __bf16* xrow  = xls + lc * XSTR;

    f32x4 acc = {0,0,0,0};
#pragma unroll 10
    for (int ks = 0; ks < 20; ++ks) {
        const int k = ks * 32 + dq;
        bf16x8 af = *reinterpret_cast<const bf16x8*>(xrow + k);
        bf16x8 bf = *reinterpret_cast<const bf16x8*>(wdrow + k);
        acc = __builtin_amdgcn_mfma_f32_16x16x32_bf16(af, bf, acc, 0, 0, 0);
    }

    // ph[kh][b][st][row][rank]
    float* pdst = ph + ((((size_t)kh * NB + b) * 64 + st) * 16) * 64;
#pragma unroll
    for (int i = 0; i < 4; ++i)
        pdst[(size_t)(quad * 4 + i) * 64 + w * 16 + lc] = acc[i];
}

// ---------------- K3: out = (ph0+ph1) @ w_up^T ----------------
// grid 512 = 8b x 64 st; 512 thr (8 waves, n-split 8). Write-bound.
__global__ __launch_bounds__(512, 4) void lora_up(const float* __restrict__ ph,
                                                  const __bf16* __restrict__ ew,
                                                  float* __restrict__ out) {
    const int bid  = blockIdx.x;
    const int b    = bid & 7;
    const int st   = bid >> 3;
    const int w    = threadIdx.x >> 6;
    const int l    = threadIdx.x & 63;
    const int quad = l >> 4;
    const int lc   = l & 15;
    const int dq   = quad * 8;

    // build A-frags: lane row = lc, ranks dq..dq+7 (ha0) and 32+dq.. (ha1)
    const float* p0 = ph + (((size_t)b * 64 + st) * 16 + lc) * 64;
    const float* p1 = p0 + (size_t)NB * 64 * 16 * 64;     // kh=1 half
    f32x4 a00 = *reinterpret_cast<const f32x4*>(p0 + dq);
    f32x4 a01 = *reinterpret_cast<const f32x4*>(p0 + dq + 4);
    f32x4 a10 = *reinterpret_cast<const f32x4*>(p0 + 32 + dq);
    f32x4 a11 = *reinterpret_cast<const f32x4*>(p0 + 32 + dq + 4);
    f32x4 b00 = *reinterpret_cast<const f32x4*>(p1 + dq);
    f32x4 b01 = *reinterpret_cast<const f32x4*>(p1 + dq + 4);
    f32x4 b10 = *reinterpret_cast<const f32x4*>(p1 + 32 + dq);
    f32x4 b11 = *reinterpret_cast<const f32x4*>(p1 + 32 + dq + 4);
    f32x4 s0 = a00 + b00, s1 = a01 + b01, s2 = a10 + b10, s3 = a11 + b11;
    bf16x8 ha0, ha1;
#pragma unroll
    for (int j = 0; j < 4; ++j) {
        ha0[j]     = (__bf16)s0[j];
        ha0[4 + j] = (__bf16)s1[j];
        ha1[j]     = (__bf16)s2[j];
        ha1[4 + j] = (__bf16)s3[j];
    }

    const __bf16* wu    = ew + (size_t)b * EMB + DOWN;
    float*        obase = out + (size_t)(b * S_ + st * 16 + quad * 4) * DOUT;

#pragma unroll 2
    for (int tt = 0; tt < 10; ++tt) {
        const int n = w + 8 * tt;
        const int o = n * 16 + lc;
        bf16x8 w0 = *reinterpret_cast<const bf16x8*>(wu + (size_t)o * RANK + dq);
        bf16x8 w1 = *reinterpret_cast<const bf16x8*>(wu + (size_t)o * RANK + 32 + dq);
        f32x4 c = {0,0,0,0};
        c = __builtin_amdgcn_mfma_f32_16x16x32_bf16(ha0, w0, c, 0, 0, 0);
        c = __builtin_amdgcn_mfma_f32_16x16x32_bf16(ha1, w1, c, 0, 0, 0);
#pragma unroll
        for (int i = 0; i < 4; ++i)
            obase[(size_t)i * DOUT + o] = c[i];
    }
}

extern "C" void kernel_launch(void* const* d_in, const int* in_sizes, int n_in,
                              void* d_out, int out_size, void* d_ws, size_t ws_size,
                              hipStream_t stream) {
    const float* x     = (const float*)d_in[0];
    const float* embed = (const float*)d_in[1];
    float*       out   = (float*)d_out;
    __bf16*      ew    = (__bf16*)d_ws;
    float*       ph    = (float*)((char*)d_ws + (size_t)NB * EMB * 2);  // after ew
    (void)in_sizes; (void)n_in; (void)out_size; (void)ws_size;

    cvt_embed<<<dim3(640), dim3(256), 0, stream>>>(embed, ew, NB * EMB / 8);
    lora_down<<<dim3(1024), dim3(256), 0, stream>>>(x, ew, ph);
    lora_up<<<dim3(512), dim3(512), 0, stream>>>(ph, ew, out);
}

// Round 7
// 109.881 us; speedup vs baseline: 1.0473x; 1.0473x over previous
//
#include <hip/hip_runtime.h>

#define NB   8
#define S_   1024
#define DIN  1280
#define RANK 64
#define DOUT 1280
#define DOWN (RANK * DIN)          // 81920
#define EMB  (DOWN + DOUT * RANK)  // 163840
#define XSTR 1288                  // x LDS row stride (bf16)
#define OSTR 268                   // out-chunk LDS row stride (fp32): 1072 B, 16B-aligned

typedef __bf16 bf16x8 __attribute__((ext_vector_type(8)));
typedef __bf16 bf16x4 __attribute__((ext_vector_type(4)));
typedef float  f32x4  __attribute__((ext_vector_type(4)));

__device__ __forceinline__ bf16x8 cvt8(float4 a, float4 b) {
    bf16x8 r;
    r[0] = (__bf16)a.x; r[1] = (__bf16)a.y; r[2] = (__bf16)a.z; r[3] = (__bf16)a.w;
    r[4] = (__bf16)b.x; r[5] = (__bf16)b.y; r[6] = (__bf16)b.z; r[7] = (__bf16)b.w;
    return r;
}

// ---------------- K1: embed fp32 -> bf16 ----------------
__global__ __launch_bounds__(256) void cvt_embed(const float* __restrict__ src,
                                                 __bf16* __restrict__ dst, int n8) {
    const int i = blockIdx.x * 256 + threadIdx.x;
    if (i < n8) {
        const float4* s = reinterpret_cast<const float4*>(src) + (size_t)i * 2;
        float4 f0 = s[0], f1 = s[1];
        *reinterpret_cast<bf16x8*>(dst + (size_t)i * 8) = cvt8(f0, f1);
    }
}

// ---------------- main: one WG = (batch b, 16 rows of S) ----------------
// Phase 0: stage x tile fp32->bf16 LDS (coalesced); wd frags for the first 8
//          k-steps prefetched BEFORE the barrier (in flight during staging).
// Phase 1: 8 waves = 4 n-tiles x 2 K-halves, 20 k-steps each, LDS pair-reduce.
// Phase 2: 5 chunks of 16 n-tiles; MFMA results -> LDS (unioned over dead x
//          tile) -> fully-coalesced float4 stores (512B runs). wu frags for
//          chunk k+1 prefetched before each chunk barrier.
__global__ __launch_bounds__(512, 4) void lora_main(const float* __restrict__ x,
                                                    const __bf16* __restrict__ ew,
                                                    float* __restrict__ out) {
    __shared__ union {
        __bf16 xls[16 * XSTR];             // 41.2 KB (phase 0/1)
        float  obuf[16 * OSTR];            // 17.2 KB (phase 2)
    } u;
    __shared__ float  pbuf[4][16][20];     // 5.1 KB
    __shared__ __bf16 hld[16][80];         // 2.6 KB

    const int b    = blockIdx.x & 7;           // batch pinned per XCD
    const int s0   = (blockIdx.x >> 3) * 16;
    const int t    = threadIdx.x;
    const int w    = t >> 6;
    const int l    = t & 63;
    const int quad = l >> 4;
    const int lc   = l & 15;
    const int dq   = quad * 8;

    const int nt = w & 3;                      // phase-1 n-tile
    const int kh = w >> 2;                     // phase-1 K half
    const __bf16* wdrow = ew + (size_t)b * EMB + (size_t)(nt * 16 + lc) * DIN + kh * 640;

    // ---- prefetch first 8 wd frags (overlap with x staging) ----
    bf16x8 pf0 = *reinterpret_cast<const bf16x8*>(wdrow + 0 * 32 + dq);
    bf16x8 pf1 = *reinterpret_cast<const bf16x8*>(wdrow + 1 * 32 + dq);
    bf16x8 pf2 = *reinterpret_cast<const bf16x8*>(wdrow + 2 * 32 + dq);
    bf16x8 pf3 = *reinterpret_cast<const bf16x8*>(wdrow + 3 * 32 + dq);
    bf16x8 pf4 = *reinterpret_cast<const bf16x8*>(wdrow + 4 * 32 + dq);
    bf16x8 pf5 = *reinterpret_cast<const bf16x8*>(wdrow + 5 * 32 + dq);
    bf16x8 pf6 = *reinterpret_cast<const bf16x8*>(wdrow + 6 * 32 + dq);
    bf16x8 pf7 = *reinterpret_cast<const bf16x8*>(wdrow + 7 * 32 + dq);

    // ---- stage x tile: 16 rows x 1280 fp32 -> bf16 LDS, coalesced ----
    {
        const int row = t >> 5;                // 32 threads per row
        const int c   = t & 31;
        const float4* src = reinterpret_cast<const float4*>(x + (size_t)(b * S_ + s0 + row) * DIN);
        __bf16* drow = u.xls + row * XSTR;
#pragma unroll
        for (int j = 0; j < 10; ++j) {
            float4 f = src[c + 32 * j];
            bf16x4 v;
            v[0]=(__bf16)f.x; v[1]=(__bf16)f.y; v[2]=(__bf16)f.z; v[3]=(__bf16)f.w;
            *reinterpret_cast<bf16x4*>(drow + (c + 32 * j) * 4) = v;
        }
    }
    __syncthreads();

    // ---- phase 1: h = x @ w_down^T ----
    const __bf16* xrow = u.xls + lc * XSTR + kh * 640;
    f32x4 acc = {0,0,0,0};
    {
        bf16x8 af;
        af = *reinterpret_cast<const bf16x8*>(xrow + 0*32 + dq); acc = __builtin_amdgcn_mfma_f32_16x16x32_bf16(af, pf0, acc, 0,0,0);
        af = *reinterpret_cast<const bf16x8*>(xrow + 1*32 + dq); acc = __builtin_amdgcn_mfma_f32_16x16x32_bf16(af, pf1, acc, 0,0,0);
        af = *reinterpret_cast<const bf16x8*>(xrow + 2*32 + dq); acc = __builtin_amdgcn_mfma_f32_16x16x32_bf16(af, pf2, acc, 0,0,0);
        af = *reinterpret_cast<const bf16x8*>(xrow + 3*32 + dq); acc = __builtin_amdgcn_mfma_f32_16x16x32_bf16(af, pf3, acc, 0,0,0);
        af = *reinterpret_cast<const bf16x8*>(xrow + 4*32 + dq); acc = __builtin_amdgcn_mfma_f32_16x16x32_bf16(af, pf4, acc, 0,0,0);
        af = *reinterpret_cast<const bf16x8*>(xrow + 5*32 + dq); acc = __builtin_amdgcn_mfma_f32_16x16x32_bf16(af, pf5, acc, 0,0,0);
        af = *reinterpret_cast<const bf16x8*>(xrow + 6*32 + dq); acc = __builtin_amdgcn_mfma_f32_16x16x32_bf16(af, pf6, acc, 0,0,0);
        af = *reinterpret_cast<const bf16x8*>(xrow + 7*32 + dq); acc = __builtin_amdgcn_mfma_f32_16x16x32_bf16(af, pf7, acc, 0,0,0);
    }
#pragma unroll
    for (int ks = 8; ks < 20; ++ks) {
        const int k = ks * 32 + dq;
        bf16x8 af = *reinterpret_cast<const bf16x8*>(xrow + k);
        bf16x8 bf = *reinterpret_cast<const bf16x8*>(wdrow + k);
        acc = __builtin_amdgcn_mfma_f32_16x16x32_bf16(af, bf, acc, 0, 0, 0);
    }

    if (kh == 1) {
#pragma unroll
        for (int i = 0; i < 4; ++i) pbuf[nt][quad * 4 + i][lc] = acc[i];
    }
    __syncthreads();
    if (kh == 0) {
#pragma unroll
        for (int i = 0; i < 4; ++i) {
            float v = acc[i] + pbuf[nt][quad * 4 + i][lc];
            hld[quad * 4 + i][nt * 16 + lc] = (__bf16)v;
        }
    }
    __syncthreads();

    // ---- phase 2: out = h @ w_up^T, LDS-transposed coalesced stores ----
    bf16x8 ha0 = *reinterpret_cast<const bf16x8*>(&hld[lc][dq]);
    bf16x8 ha1 = *reinterpret_cast<const bf16x8*>(&hld[lc][32 + dq]);
    const __bf16* wu = ew + (size_t)b * EMB + DOWN;
    float* orow_base = out + (size_t)(b * S_ + s0) * DOUT;

    const int frow = t >> 5;                   // flush row, 32 thr/row
    const int fc   = t & 31;

    // preload chunk 0 wu frags (2 n-tiles per wave)
    bf16x8 w00, w01, w10, w11;
    {
        const int o0 = (w * 2 + 0) * 16 + lc;
        const int o1 = (w * 2 + 1) * 16 + lc;
        w00 = *reinterpret_cast<const bf16x8*>(wu + (size_t)o0 * RANK + dq);
        w01 = *reinterpret_cast<const bf16x8*>(wu + (size_t)o0 * RANK + 32 + dq);
        w10 = *reinterpret_cast<const bf16x8*>(wu + (size_t)o1 * RANK + dq);
        w11 = *reinterpret_cast<const bf16x8*>(wu + (size_t)o1 * RANK + 32 + dq);
    }

#pragma unroll
    for (int chunk = 0; chunk < 5; ++chunk) {
        if (chunk) __syncthreads();            // prev flush reads done before overwrite

        f32x4 c0 = {0,0,0,0}, c1 = {0,0,0,0};
        c0 = __builtin_amdgcn_mfma_f32_16x16x32_bf16(ha0, w00, c0, 0, 0, 0);
        c0 = __builtin_amdgcn_mfma_f32_16x16x32_bf16(ha1, w01, c0, 0, 0, 0);
        c1 = __builtin_amdgcn_mfma_f32_16x16x32_bf16(ha0, w10, c1, 0, 0, 0);
        c1 = __builtin_amdgcn_mfma_f32_16x16x32_bf16(ha1, w11, c1, 0, 0, 0);

        const int nl0 = w * 2, nl1 = w * 2 + 1;
#pragma unroll
        for (int i = 0; i < 4; ++i) {
            u.obuf[(quad * 4 + i) * OSTR + nl0 * 16 + lc] = c0[i];
            u.obuf[(quad * 4 + i) * OSTR + nl1 * 16 + lc] = c1[i];
        }

        // prefetch next chunk's wu frags before the barrier
        if (chunk < 4) {
            const int o0 = ((chunk + 1) * 16 + w * 2 + 0) * 16 + lc;
            const int o1 = ((chunk + 1) * 16 + w * 2 + 1) * 16 + lc;
            w00 = *reinterpret_cast<const bf16x8*>(wu + (size_t)o0 * RANK + dq);
            w01 = *reinterpret_cast<const bf16x8*>(wu + (size_t)o0 * RANK + 32 + dq);
            w10 = *reinterpret_cast<const bf16x8*>(wu + (size_t)o1 * RANK + dq);
            w11 = *reinterpret_cast<const bf16x8*>(wu + (size_t)o1 * RANK + 32 + dq);
        }
        __syncthreads();

        // coalesced flush: 16 rows x 256 cols fp32, 2 float4 per thread
        const float* orow = u.obuf + frow * OSTR;
        float4 v0 = *reinterpret_cast<const float4*>(orow + fc * 4);
        float4 v1 = *reinterpret_cast<const float4*>(orow + (fc + 32) * 4);
        float* dst = orow_base + (size_t)frow * DOUT + chunk * 256;
        *reinterpret_cast<float4*>(dst + fc * 4) = v0;
        *reinterpret_cast<float4*>(dst + (fc + 32) * 4) = v1;
    }
}

extern "C" void kernel_launch(void* const* d_in, const int* in_sizes, int n_in,
                              void* d_out, int out_size, void* d_ws, size_t ws_size,
                              hipStream_t stream) {
    const float* x     = (const float*)d_in[0];
    const float* embed = (const float*)d_in[1];
    float*       out   = (float*)d_out;
    __bf16*      ew    = (__bf16*)d_ws;          // 8 x 163840 bf16 = 2.6 MB
    (void)in_sizes; (void)n_in; (void)out_size; (void)ws_size;

    cvt_embed<<<dim3(640), dim3(256), 0, stream>>>(embed, ew, NB * EMB / 8);
    lora_main<<<dim3(512), dim3(512), 0, stream>>>(x, ew, out);
}